// Round 10
// baseline (292.932 us; speedup 1.0000x reference)
//
#include <hip/hip_runtime.h>
#include <hip/hip_bf16.h>
#include <math.h>

#define BB 2
#define CC 128
#define HH 96
#define WW 96
#define HWX (HH*WW)        // 9216
#define KTOT (CC*9)        // 1152
#define OC 128
#define KHALF 576          // K split: 64 channels per half
#define ROWH 600           // 576 + 24 pad; 1200 B row stride (16B-aligned)

#define NWBF  (KTOT*OC)    // 147456
#define NWHL  (KTOT*32)    // 36864 (offset weights, o padded 21->32)

typedef __attribute__((ext_vector_type(8))) __bf16 bf16x8;
typedef __attribute__((ext_vector_type(4))) float floatx4;

// ---------------- K0: prep — conv_w->bf16 + offset-weights hi/lo split (o-major) ------
__global__ __launch_bounds__(256) void prep_kernel(const float* __restrict__ cw,
                                                   const float* __restrict__ pw,
                                                   const float* __restrict__ aw,
                                                   __bf16* __restrict__ wbf,
                                                   __bf16* __restrict__ whi,
                                                   __bf16* __restrict__ wlo)
{
    int t = blockIdx.x * 256 + threadIdx.x;
    if (t < NWBF) {
        wbf[t] = (__bf16)cw[t];
    } else if (t < NWBF + NWHL) {
        int r = t - NWBF;                 // r = o*1152 + k, o in [0,32)
        int o = r / KTOT;
        float v = 0.f;
        if (o < 18)      v = pw[r];
        else if (o < 21) v = aw[r - 18 * KTOT];
        __bf16 hi = (__bf16)v;
        whi[r] = hi;
        wlo[r] = (__bf16)(v - (float)hi);
    }
}

// ---------------- K1: offsets conv as split-bf16 MFMA GEMM (full fp32 accuracy) -------
// 576 blocks x 32 px; 4 waves = 2 m-tiles x 2 n-tiles; K=1152 in 2 halves.
// acc += Ah*Bh + Ah*Bl + Al*Bh + Al*Bl  (error ~1e-5 relative -> no mask-flip risk)
__global__ __launch_bounds__(256) void offs_kernel(
    const float* __restrict__ x, const __bf16* __restrict__ whi,
    const __bf16* __restrict__ wlo, float* __restrict__ offw,
    float* __restrict__ adw)
{
    __shared__ __align__(16) __bf16 ah[32 * ROWH];   // 37.5 KB
    __shared__ __align__(16) __bf16 al[32 * ROWH];   // 37.5 KB

    int tid = threadIdx.x;
    int gid0 = blockIdx.x * 32;
    int b  = gid0 / HWX;
    int r0 = gid0 - b * HWX;
    int i  = r0 / WW;
    int j0 = r0 % WW;

    int wv = tid >> 6, lane = tid & 63;
    int quad = lane >> 4, l15 = lane & 15;
    int mt = wv & 1;                 // m-tile (pixels mt*16..mt*16+15)
    int nt = wv >> 1;                // n-tile (o = nt*16 + l15)
    floatx4 acc = {0.f, 0.f, 0.f, 0.f};
    const __bf16* bh = whi + (size_t)(nt * 16 + l15) * KTOT;
    const __bf16* bl = wlo + (size_t)(nt * 16 + l15) * KTOT;
    const __bf16* arh = &ah[(mt * 16 + l15) * ROWH];
    const __bf16* arl = &al[(mt * 16 + l15) * ROWH];
    const float* xb = x + (size_t)b * CC * HWX;

    for (int h = 0; h < 2; ++h) {
        // stage A-half: kl = cl*9 + tap, c = h*64 + cl; im2col of 3x3 pad-1 conv
        for (int t = tid; t < 32 * KHALF; t += 256) {
            int px = t & 31;
            int rest = t >> 5;            // 0..575
            int cl = rest / 9;
            int tap = rest - cl * 9;
            int di = tap / 3, dj = tap - di * 3;
            int ri = i - 1 + di;
            int cj = j0 + px - 1 + dj;
            float v = 0.f;
            if (ri >= 0 && ri < HH && cj >= 0 && cj < WW)
                v = xb[(size_t)(h * 64 + cl) * HWX + ri * WW + cj];
            __bf16 hi = (__bf16)v;
            ah[px * ROWH + rest] = hi;
            al[px * ROWH + rest] = (__bf16)(v - (float)hi);
        }
        __syncthreads();

        for (int kt = 0; kt < 18; ++kt) {
            int kl = kt * 32 + quad * 8;
            int kg = h * KHALF + kl;
            bf16x8 Ah = *(const bf16x8*)(arh + kl);   // vector LDS reads (verified)
            bf16x8 Al = *(const bf16x8*)(arl + kl);
            bf16x8 Bh = *(const bf16x8*)(bh + kg);    // vector global loads (verified)
            bf16x8 Bl = *(const bf16x8*)(bl + kg);
            acc = __builtin_amdgcn_mfma_f32_16x16x32_bf16(Ah, Bh, acc, 0, 0, 0);
            acc = __builtin_amdgcn_mfma_f32_16x16x32_bf16(Ah, Bl, acc, 0, 0, 0);
            acc = __builtin_amdgcn_mfma_f32_16x16x32_bf16(Al, Bh, acc, 0, 0, 0);
            acc = __builtin_amdgcn_mfma_f32_16x16x32_bf16(Al, Bl, acc, 0, 0, 0);
        }
        __syncthreads();
    }

    int o = nt * 16 + l15;
#pragma unroll
    for (int rr = 0; rr < 4; ++rr) {
        int px = mt * 16 + quad * 4 + rr;     // D row (verified)
        int j = j0 + px;
        if (o < 18)
            offw[((b * 18 + o) * HH + i) * WW + j] = acc[rr];
        else if (o < 21)
            adw[((b * 3 + (o - 18)) * HH + i) * WW + j] = acc[rr];
    }
}

// ---------------- K2: sampling + MFMA GEMM — EXACT round-9 deform (111 µs verified) ---
__global__ __launch_bounds__(256) void deform_kernel(
    const float* __restrict__ x, const float* __restrict__ offw,
    const float* __restrict__ adw, const float* __restrict__ pb,
    const float* __restrict__ ab, const __bf16* __restrict__ wbf,
    float* __restrict__ out)
{
    __shared__ __align__(16) __bf16 xoff[32 * ROWH];
    __shared__ int4   qidx[288];
    __shared__ float4 gwt[288];

    int tid = threadIdx.x;
    int gid0 = blockIdx.x * 32;
    int b  = gid0 / HWX;
    int r0 = gid0 - b * HWX;
    int i  = r0 / WW;
    int j0 = r0 % WW;

    for (int t = tid; t < 288; t += 256) {
        int px = t / 9, n = t % 9;
        int j = j0 + px;
        float offx = offw[((b * 18 + n) * HH + i) * WW + j] + pb[n];
        float offy = offw[((b * 18 + 9 + n) * HH + i) * WW + j] + pb[9 + n];
        float zad  = adw[((b * 3 + (n % 3)) * HH + i) * WW + j] + ab[n % 3];
        float ad   = 2.f * (1.f - 1.f / (1.f + expf(-zad)));
        float pnx = (float)(n / 3 - 1), pny = (float)(n % 3 - 1);
        float pxf = (float)(i + 1) + pnx * (1.f + ad) + offx;
        float pyf = (float)(j + 1) + pny * (1.f + ad) + offy;
        float flx = floorf(pxf), fly = floorf(pyf);
        float qltx = fminf(fmaxf(flx, 0.f), 97.f);
        float qlty = fminf(fmaxf(fly, 0.f), 97.f);
        float qrbx = fminf(fmaxf(flx + 1.f, 0.f), 97.f);
        float qrby = fminf(fmaxf(fly + 1.f, 0.f), 97.f);
        bool mx = (pxf < 1.f) || (pxf > 96.f);
        bool my = (pyf < 1.f) || (pyf > 96.f);
        float pxm = mx ? flx : pxf; pxm = fminf(fmaxf(pxm, 0.f), 97.f);
        float pym = my ? fly : pyf; pym = fminf(fmaxf(pym, 0.f), 97.f);
        float glt = (1.f + (qltx - pxm)) * (1.f + (qlty - pym));
        float grb = (1.f - (qrbx - pxm)) * (1.f - (qrby - pym));
        float glb = (1.f + (qltx - pxm)) * (1.f - (qrby - pym));
        float grt = (1.f - (qrbx - pxm)) * (1.f + (qlty - pym));
        qidx[t] = make_int4((int)qltx, (int)qlty, (int)qrbx, (int)qrby);
        gwt[t]  = make_float4(glt, grb, glb, grt);
    }
    __syncthreads();

    int wv = tid >> 6, lane = tid & 63;
    int quad = lane >> 4, l15 = lane & 15;
    int o0 = wv * 32 + l15;
    int o1 = wv * 32 + 16 + l15;
    floatx4 acc00 = {0,0,0,0}, acc01 = {0,0,0,0};
    floatx4 acc10 = {0,0,0,0}, acc11 = {0,0,0,0};
    const __bf16* w0b = wbf + (size_t)o0 * KTOT;
    const __bf16* w1b = wbf + (size_t)o1 * KTOT;
    const float* xb = x + (size_t)b * CC * HWX;
    const __bf16* arow0 = &xoff[l15 * ROWH];
    const __bf16* arow1 = &xoff[(16 + l15) * ROWH];

    for (int h = 0; h < 2; ++h) {
        for (int t = tid; t < 32 * KHALF; t += 256) {
            int px = t & 31;
            int rest = t >> 5;
            int n  = rest >> 6;
            int cl = rest & 63;
            int pidx = px * 9 + n;
            int4 q = qidx[pidx];
            float4 g = gwt[pidx];
            const float* xc = xb + (size_t)(h * 64 + cl) * HWX;
            bool rx_lt = (q.x >= 1) & (q.x <= 96);
            bool rx_rb = (q.z >= 1) & (q.z <= 96);
            bool cy_lt = (q.y >= 1) & (q.y <= 96);
            bool cy_rb = (q.w >= 1) & (q.w <= 96);
            float vlt = (rx_lt && cy_lt) ? xc[(q.x - 1) * WW + (q.y - 1)] : 0.f;
            float vrb = (rx_rb && cy_rb) ? xc[(q.z - 1) * WW + (q.w - 1)] : 0.f;
            float vlb = (rx_lt && cy_rb) ? xc[(q.x - 1) * WW + (q.w - 1)] : 0.f;
            float vrt = (rx_rb && cy_lt) ? xc[(q.z - 1) * WW + (q.y - 1)] : 0.f;
            float val = g.x * vlt + g.y * vrb + g.z * vlb + g.w * vrt;
            xoff[px * ROWH + cl * 9 + n] = (__bf16)val;
        }
        __syncthreads();

        for (int kt = 0; kt < 18; ++kt) {
            int kl = kt * 32 + quad * 8;
            int kg = h * KHALF + kl;
            bf16x8 a0 = *(const bf16x8*)(arow0 + kl);
            bf16x8 a1 = *(const bf16x8*)(arow1 + kl);
            bf16x8 b0 = *(const bf16x8*)(w0b + kg);
            bf16x8 b1 = *(const bf16x8*)(w1b + kg);
            acc00 = __builtin_amdgcn_mfma_f32_16x16x32_bf16(a0, b0, acc00, 0, 0, 0);
            acc01 = __builtin_amdgcn_mfma_f32_16x16x32_bf16(a0, b1, acc01, 0, 0, 0);
            acc10 = __builtin_amdgcn_mfma_f32_16x16x32_bf16(a1, b0, acc10, 0, 0, 0);
            acc11 = __builtin_amdgcn_mfma_f32_16x16x32_bf16(a1, b1, acc11, 0, 0, 0);
        }
        __syncthreads();
    }

#pragma unroll
    for (int rr = 0; rr < 4; ++rr) {
        int m0 = quad * 4 + rr;
        int ja = j0 + m0, jb = j0 + 16 + m0;
        out[((b * OC + o0) * HH + i) * WW + ja] = acc00[rr];
        out[((b * OC + o1) * HH + i) * WW + ja] = acc01[rr];
        out[((b * OC + o0) * HH + i) * WW + jb] = acc10[rr];
        out[((b * OC + o1) * HH + i) * WW + jb] = acc11[rr];
    }
}

extern "C" void kernel_launch(void* const* d_in, const int* in_sizes, int n_in,
                              void* d_out, int out_size, void* d_ws, size_t ws_size,
                              hipStream_t stream)
{
    const float* x  = (const float*)d_in[0];
    const float* cw = (const float*)d_in[1];
    const float* pw = (const float*)d_in[2];
    const float* pb = (const float*)d_in[3];
    const float* aw = (const float*)d_in[4];
    const float* ab = (const float*)d_in[5];
    float* out = (float*)d_out;

    char* ws = (char*)d_ws;
    float*  offw = (float*)ws;                      // 331776 fp32 raw sums
    float*  adw  = offw + BB * 18 * HWX;            // 55296 fp32 raw sums
    __bf16* wbf  = (__bf16*)(adw + BB * 3 * HWX);   // 147456 bf16
    __bf16* whi  = wbf + NWBF;                      // 36864 bf16
    __bf16* wlo  = whi + NWHL;                      // 36864 bf16

    int nprep = NWBF + NWHL;
    prep_kernel<<<(nprep + 255) / 256, 256, 0, stream>>>(cw, pw, aw, wbf, whi, wlo);
    offs_kernel<<<(BB * HWX) / 32, 256, 0, stream>>>(x, whi, wlo, offw, adw);
    deform_kernel<<<(BB * HWX) / 32, 256, 0, stream>>>(x, offw, adw, pb, ab, wbf, out);
}

// Round 11
// 214.437 us; speedup vs baseline: 1.3661x; 1.3661x over previous
//
#include <hip/hip_runtime.h>
#include <hip/hip_bf16.h>
#include <math.h>

#define BB 2
#define CC 128
#define HH 96
#define WW 96
#define HWX (HH*WW)        // 9216
#define KTOT (CC*9)        // 1152
#define OC 128
#define KHALF 576          // deform K split: 64 channels per half
#define ROWH 600           // 576 + 24 pad; 1200 B row stride (16B-aligned)

#define NWBF  (KTOT*OC)    // 147456
#define NWP   (32*KTOT)    // 36864  (offset weights, o padded 21->32, permuted k)

typedef __attribute__((ext_vector_type(8))) __bf16 bf16x8;
typedef __attribute__((ext_vector_type(4))) float floatx4;

// ---------------- K0: prep — conv_w->bf16 + permuted hi/lo offset weights -------------
// Permuted k-order matches offs_kernel's step order: kk = s*32 + r, s = cgroup*9 + tap,
// c = cgroup*32 + r  (so B rows stream contiguously per MFMA step).
__global__ __launch_bounds__(256) void prep_kernel(const float* __restrict__ cw,
                                                   const float* __restrict__ pw,
                                                   const float* __restrict__ aw,
                                                   __bf16* __restrict__ wbf,
                                                   __bf16* __restrict__ whiP,
                                                   __bf16* __restrict__ wloP)
{
    int t = blockIdx.x * 256 + threadIdx.x;
    if (t < NWBF) {
        wbf[t] = (__bf16)cw[t];
    } else if (t < NWBF + NWP) {
        int r = t - NWBF;                 // r = o*1152 + kk
        int o  = r / KTOT;
        int kk = r - o * KTOT;
        int s  = kk >> 5;                 // step 0..35
        int rr = kk & 31;
        int tap = s % 9;
        int cg  = s / 9;
        int c   = cg * 32 + rr;
        float v = 0.f;
        if (o < 18)      v = pw[o * KTOT + c * 9 + tap];
        else if (o < 21) v = aw[(o - 18) * KTOT + c * 9 + tap];
        __bf16 hi = (__bf16)v;
        whiP[r] = hi;
        wloP[r] = (__bf16)(v - (float)hi);
    }
}

// ---------------- K1: offsets conv — shared fp32 patch, shift-read MFMA (no im2col) ---
// 576 blocks x 32 px, 4 waves = 2 m-tiles x 2 n-tiles. Patch staged ONCE per c-half
// (64c x 3 rows x 34 cols fp32, 26 KB); A hi/lo formed in registers per step.
__global__ __launch_bounds__(256) void offs_kernel(
    const float* __restrict__ x, const __bf16* __restrict__ whiP,
    const __bf16* __restrict__ wloP, float* __restrict__ offw,
    float* __restrict__ adw)
{
    __shared__ float patch[64 * 3 * 34];   // idx = (cl*3 + ri)*34 + cc

    int tid = threadIdx.x;
    int gid0 = blockIdx.x * 32;
    int b  = gid0 / HWX;
    int r0 = gid0 - b * HWX;
    int i  = r0 / WW;
    int j0 = r0 % WW;

    int wv = tid >> 6, lane = tid & 63;
    int quad = lane >> 4, l15 = lane & 15;
    int mt = wv & 1;                  // pixel tile (px mt*16 .. mt*16+15)
    int nt = wv >> 1;                 // o tile
    int o  = nt * 16 + l15;
    floatx4 acc = {0.f, 0.f, 0.f, 0.f};
    const __bf16* bh = whiP + (size_t)o * KTOT;
    const __bf16* bl = wloP + (size_t)o * KTOT;
    const float* xb = x + (size_t)b * CC * HWX;

    for (int h = 0; h < 2; ++h) {
        for (int t = tid; t < 6528; t += 256) {
            int cl = t / 102;              // 102 = 3*34
            int rc = t - cl * 102;
            int ri = rc / 34, cc = rc - ri * 34;
            int gi = i - 1 + ri, gj = j0 - 1 + cc;
            float v = 0.f;
            if (gi >= 0 && gi < HH && gj >= 0 && gj < WW)
                v = xb[(size_t)(h * 64 + cl) * HWX + gi * WW + gj];
            patch[t] = v;
        }
        __syncthreads();

        for (int s = 0; s < 18; ++s) {     // s = ct*9 + tap
            int ct = s / 9, tap = s - ct * 9;
            int di = tap / 3, dj = tap - di * 3;
            const float* ap = &patch[((ct * 32 + quad * 8) * 3 + di) * 34
                                     + (mt * 16 + l15) + dj];
            bf16x8 Ah, Al;
#pragma unroll
            for (int j = 0; j < 8; ++j) {
                float v = ap[j * 102];     // stride 102 dw -> ds_read2-pairable
                __bf16 hv = (__bf16)v;
                Ah[j] = hv;
                Al[j] = (__bf16)(v - (float)hv);
            }
            int kg = (h * 18 + s) * 32 + quad * 8;
            bf16x8 Bh = *(const bf16x8*)(bh + kg);
            bf16x8 Bl = *(const bf16x8*)(bl + kg);
            acc = __builtin_amdgcn_mfma_f32_16x16x32_bf16(Ah, Bh, acc, 0, 0, 0);
            acc = __builtin_amdgcn_mfma_f32_16x16x32_bf16(Ah, Bl, acc, 0, 0, 0);
            acc = __builtin_amdgcn_mfma_f32_16x16x32_bf16(Al, Bh, acc, 0, 0, 0);
            acc = __builtin_amdgcn_mfma_f32_16x16x32_bf16(Al, Bl, acc, 0, 0, 0);
        }
        __syncthreads();
    }

    if (o < 21) {
#pragma unroll
        for (int rr = 0; rr < 4; ++rr) {
            int px = mt * 16 + quad * 4 + rr;      // D row (verified)
            int j = j0 + px;
            if (o < 18) offw[((b * 18 + o) * HH + i) * WW + j] = acc[rr];
            else        adw[((b * 3 + (o - 18)) * HH + i) * WW + j] = acc[rr];
        }
    }
}

// ---------------- K2: sampling + MFMA GEMM — M=16/block for 2x occupancy --------------
__global__ __launch_bounds__(256) void deform_kernel(
    const float* __restrict__ x, const float* __restrict__ offw,
    const float* __restrict__ adw, const float* __restrict__ pb,
    const float* __restrict__ ab, const __bf16* __restrict__ wbf,
    float* __restrict__ out)
{
    __shared__ __align__(16) __bf16 xoff[16 * ROWH];   // 19.2 KB
    __shared__ int4   qidx[144];
    __shared__ float4 gwt[144];

    int tid = threadIdx.x;
    int gid0 = blockIdx.x * 16;
    int b  = gid0 / HWX;
    int r0 = gid0 - b * HWX;
    int i  = r0 / WW;
    int j0 = r0 % WW;

    if (tid < 144) {
        int t = tid;
        int px = t / 9, n = t % 9;
        int j = j0 + px;
        float offx = offw[((b * 18 + n) * HH + i) * WW + j] + pb[n];
        float offy = offw[((b * 18 + 9 + n) * HH + i) * WW + j] + pb[9 + n];
        float zad  = adw[((b * 3 + (n % 3)) * HH + i) * WW + j] + ab[n % 3];
        float ad   = 2.f * (1.f - 1.f / (1.f + expf(-zad)));
        float pnx = (float)(n / 3 - 1), pny = (float)(n % 3 - 1);
        float pxf = (float)(i + 1) + pnx * (1.f + ad) + offx;
        float pyf = (float)(j + 1) + pny * (1.f + ad) + offy;
        float flx = floorf(pxf), fly = floorf(pyf);
        float qltx = fminf(fmaxf(flx, 0.f), 97.f);
        float qlty = fminf(fmaxf(fly, 0.f), 97.f);
        float qrbx = fminf(fmaxf(flx + 1.f, 0.f), 97.f);
        float qrby = fminf(fmaxf(fly + 1.f, 0.f), 97.f);
        bool mx = (pxf < 1.f) || (pxf > 96.f);
        bool my = (pyf < 1.f) || (pyf > 96.f);
        float pxm = mx ? flx : pxf; pxm = fminf(fmaxf(pxm, 0.f), 97.f);
        float pym = my ? fly : pyf; pym = fminf(fmaxf(pym, 0.f), 97.f);
        float glt = (1.f + (qltx - pxm)) * (1.f + (qlty - pym));
        float grb = (1.f - (qrbx - pxm)) * (1.f - (qrby - pym));
        float glb = (1.f + (qltx - pxm)) * (1.f - (qrby - pym));
        float grt = (1.f - (qrbx - pxm)) * (1.f + (qlty - pym));
        qidx[t] = make_int4((int)qltx, (int)qlty, (int)qrbx, (int)qrby);
        gwt[t]  = make_float4(glt, grb, glb, grt);
    }
    __syncthreads();

    int wv = tid >> 6, lane = tid & 63;
    int quad = lane >> 4, l15 = lane & 15;
    int o0 = wv * 32 + l15;
    int o1 = wv * 32 + 16 + l15;
    floatx4 acc0 = {0,0,0,0}, acc1 = {0,0,0,0};
    const __bf16* w0b = wbf + (size_t)o0 * KTOT;
    const __bf16* w1b = wbf + (size_t)o1 * KTOT;
    const float* xb = x + (size_t)b * CC * HWX;
    const __bf16* arow = &xoff[l15 * ROWH];

    for (int h = 0; h < 2; ++h) {
        for (int t = tid; t < 16 * KHALF; t += 256) {   // 36 iters
            int px = t & 15;
            int rest = t >> 4;           // 0..575
            int n  = rest >> 6;
            int cl = rest & 63;
            int pidx = px * 9 + n;
            int4 q = qidx[pidx];
            float4 g = gwt[pidx];
            const float* xc = xb + (size_t)(h * 64 + cl) * HWX;
            bool rx_lt = (q.x >= 1) & (q.x <= 96);
            bool rx_rb = (q.z >= 1) & (q.z <= 96);
            bool cy_lt = (q.y >= 1) & (q.y <= 96);
            bool cy_rb = (q.w >= 1) & (q.w <= 96);
            float vlt = (rx_lt && cy_lt) ? xc[(q.x - 1) * WW + (q.y - 1)] : 0.f;
            float vrb = (rx_rb && cy_rb) ? xc[(q.z - 1) * WW + (q.w - 1)] : 0.f;
            float vlb = (rx_lt && cy_rb) ? xc[(q.x - 1) * WW + (q.w - 1)] : 0.f;
            float vrt = (rx_rb && cy_lt) ? xc[(q.z - 1) * WW + (q.y - 1)] : 0.f;
            float val = g.x * vlt + g.y * vrb + g.z * vlb + g.w * vrt;
            xoff[px * ROWH + cl * 9 + n] = (__bf16)val;
        }
        __syncthreads();

        for (int kt = 0; kt < 18; ++kt) {
            int kl = kt * 32 + quad * 8;
            int kg = h * KHALF + kl;
            bf16x8 a0 = *(const bf16x8*)(arow + kl);     // vector LDS reads (verified)
            bf16x8 b0 = *(const bf16x8*)(w0b + kg);      // vector global loads (verified)
            bf16x8 b1 = *(const bf16x8*)(w1b + kg);
            acc0 = __builtin_amdgcn_mfma_f32_16x16x32_bf16(a0, b0, acc0, 0, 0, 0);
            acc1 = __builtin_amdgcn_mfma_f32_16x16x32_bf16(a0, b1, acc1, 0, 0, 0);
        }
        __syncthreads();
    }

#pragma unroll
    for (int rr = 0; rr < 4; ++rr) {
        int m = quad * 4 + rr;                 // D row (verified)
        int j = j0 + m;
        out[((b * OC + o0) * HH + i) * WW + j] = acc0[rr];
        out[((b * OC + o1) * HH + i) * WW + j] = acc1[rr];
    }
}

extern "C" void kernel_launch(void* const* d_in, const int* in_sizes, int n_in,
                              void* d_out, int out_size, void* d_ws, size_t ws_size,
                              hipStream_t stream)
{
    const float* x  = (const float*)d_in[0];
    const float* cw = (const float*)d_in[1];
    const float* pw = (const float*)d_in[2];
    const float* pb = (const float*)d_in[3];
    const float* aw = (const float*)d_in[4];
    const float* ab = (const float*)d_in[5];
    float* out = (float*)d_out;

    char* ws = (char*)d_ws;
    float*  offw = (float*)ws;                      // 331776 fp32 raw sums
    float*  adw  = offw + BB * 18 * HWX;            // 55296 fp32 raw sums
    __bf16* wbf  = (__bf16*)(adw + BB * 3 * HWX);   // 147456 bf16
    __bf16* whiP = wbf + NWBF;                      // 36864 bf16 (permuted)
    __bf16* wloP = whiP + NWP;                      // 36864 bf16 (permuted)

    int nprep = NWBF + NWP;
    prep_kernel<<<(nprep + 255) / 256, 256, 0, stream>>>(cw, pw, aw, wbf, whiP, wloP);
    offs_kernel<<<(BB * HWX) / 32, 256, 0, stream>>>(x, whiP, wloP, offw, adw);
    deform_kernel<<<(BB * HWX) / 16, 256, 0, stream>>>(x, offw, adw, pb, ab, wbf, out);
}